// Round 9
// baseline (881.756 us; speedup 1.0000x reference)
//
#include <hip/hip_runtime.h>
#include <stdint.h>

// Problem constants (from reference)
#define NN 500000          // nodes
#define HH 256             // hidden
#define MBLK 32            // nodes per block
#define NBLK (NN / MBLK)   // 15625 exact -- NO tail
#define NCH 17             // weight chunks: W1:1, W2:8, W3:8
// ws layout: u16[NCH][2 planes(hi,lo)][256 n][32 k'] = 17 x 32KB = 544KB,
// L2-resident; B-frags read straight from global (no LDS staging, no k-loop
// barriers). hbuf: h activations as TWO bf16 planes [32 rows][256 k] u16 each
// (16KB x2 = 32KB) with 16B-granule XOR swizzle -> A-frags are raw
// ds_read_b128, zero unpack VALU.

typedef short short8 __attribute__((ext_vector_type(8)));
typedef float floatx4 __attribute__((ext_vector_type(4)));

union fu32 { float f; uint32_t u; };

__device__ __forceinline__ unsigned short f2bf(float f) {
  fu32 v; v.f = f;
  uint32_t r = v.u + 0x7fffu + ((v.u >> 16) & 1u);   // RNE (pack kernel only)
  return (unsigned short)(r >> 16);
}
__device__ __forceinline__ float bf2f(unsigned short h) {
  fu32 v; v.u = ((uint32_t)h) << 16;
  return v.f;
}
__device__ __forceinline__ float tanh_fast(float x) {
  float xc = fminf(fmaxf(x, -9.0f), 9.0f);           // tanh(9) == 1 - 3e-8
  float e = __expf(2.0f * xc);
  return __fdividef(e - 1.0f, e + 1.0f);
}
__device__ __forceinline__ float log_sigmoid_f(float x) {
  return fminf(x, 0.0f) - log1pf(__expf(-fabsf(x)));
}

// ---------------------------------------------------------------------------
// Pre-kernel: W1/W2/W3 (fp32 [k][n]) -> hi/lo bf16 planes in ws.
// Runs every launch (d_ws is re-poisoned by the harness).
// ---------------------------------------------------------------------------
__global__ void __launch_bounds__(256)
pack_weights(const float* __restrict__ W1, const float* __restrict__ W2,
             const float* __restrict__ W3, uint16_t* __restrict__ ws16) {
  int t = blockIdx.x * 256 + threadIdx.x;
  if (t >= NCH * 8192) return;
  int ch = t >> 13;             // chunk
  int r = t & 8191;
  int n  = r & 255;             // fast index -> coalesced source reads
  int kp = r >> 8;              // 0..31
  float w;
  if (ch == 0)      w = W1[kp * HH + n];
  else if (ch <= 8) w = W2[((ch - 1) * 32 + kp) * HH + n];
  else              w = W3[((ch - 9) * 32 + kp) * HH + n];
  unsigned short hi = f2bf(w);
  unsigned short lo = f2bf(w - bf2f(hi));
  uint16_t* p = ws16 + (size_t)ch * 16384 + n * 32 + kp;
  p[0]    = hi;                 // plane 0
  p[8192] = lo;                 // plane 1
}

// One k-step (k=32): 3-pass hi/lo split MFMA, B from GLOBAL (L2-hit).
// D = Ahi*Bhi + Alo*Bhi + Ahi*Blo (dropped Alo*Blo ~2^-16 rel/term).
#define KSTEP_G(AHI, ALO, WG)                                                  \
  {                                                                            \
    const uint16_t* wg_ = (WG);                                                \
    _Pragma("unroll")                                                          \
    for (int nt = 0; nt < 2; ++nt) {                                           \
      short8 bhi = *(const short8*)(wg_ + woff + nt * 512);                    \
      short8 blo = *(const short8*)(wg_ + 8192 + woff + nt * 512);             \
      _Pragma("unroll")                                                        \
      for (int mt = 0; mt < 2; ++mt) {                                         \
        acc[mt][nt] = __builtin_amdgcn_mfma_f32_16x16x32_bf16(AHI[mt], bhi, acc[mt][nt], 0, 0, 0); \
        acc[mt][nt] = __builtin_amdgcn_mfma_f32_16x16x32_bf16(ALO[mt], bhi, acc[mt][nt], 0, 0, 0); \
        acc[mt][nt] = __builtin_amdgcn_mfma_f32_16x16x32_bf16(AHI[mt], blo, acc[mt][nt], 0, 0, 0); \
      }                                                                        \
    }                                                                          \
  }

#define ZEROACC()                                                              \
  {                                                                            \
    _Pragma("unroll") for (int mt = 0; mt < 2; ++mt)                           \
        _Pragma("unroll") for (int nt = 0; nt < 2; ++nt)                       \
            acc[mt][nt] = (floatx4){0.f, 0.f, 0.f, 0.f};                       \
  }

// bias + tanh + truncation hi/lo split, write both bf16 planes (b16 stores).
// hi = top 16 bits of tv (truncation); lo_f = tv - hi_f is EXACT in fp32;
// lo = trunc-bf16(lo_f). Total captured mantissa ~16 bits, cheap: ~4 VALU.
// C/D layout (m89): col = lane&15 (c), row = q*4+rr (+mt*16).
#define EPILOGUE_SPLIT(BIAS)                                                   \
  {                                                                            \
    _Pragma("unroll")                                                          \
    for (int nt = 0; nt < 2; ++nt) {                                           \
      const int k = wv * 32 + nt * 16 + c;                                     \
      float bv = (BIAS)[k];                                                    \
      _Pragma("unroll")                                                        \
      for (int mt = 0; mt < 2; ++mt) {                                         \
        _Pragma("unroll")                                                      \
        for (int rr = 0; rr < 4; ++rr) {                                       \
          float tv = tanh_fast(acc[mt][nt][rr] + bv);                          \
          const int row = mt * 16 + q * 4 + rr;                                \
          const int idx = row * 256 + ((((k >> 3) ^ (row & 15)) << 3) | (k & 7)); \
          fu32 a_; a_.f = tv;                                                  \
          hbuf[idx] = (uint16_t)(a_.u >> 16);            /* hi plane */        \
          fu32 h_; h_.u = a_.u & 0xffff0000u;                                  \
          fu32 l_; l_.f = tv - h_.f;                                           \
          hbuf[8192 + idx] = (uint16_t)(l_.u >> 16);     /* lo plane */        \
        }                                                                      \
      }                                                                        \
    }                                                                          \
  }

// ---------------------------------------------------------------------------
// Fused 4-layer MLP. Block = 512 thr (8 waves, all in n-dim), 32 nodes/block.
// Per wave: 32 rows x 32 cols (acc 2x2 fragments), hi/lo 3-pass MFMA.
// LDS 32KB -> 4 blocks/CU = 32 waves/CU (100% occupancy target).
// A-frags: raw ds_read_b128 from the hi/lo planes (granule-XOR swizzled;
// write-granule g^(row&15) == read-granule (kc*4+q)^c since row&15==c --
// same involution both sides; 2-way bank aliasing only = free per m136).
// ---------------------------------------------------------------------------
__global__ void __launch_bounds__(512, 8)
mlp_fused(const float* __restrict__ ea, const float* __restrict__ b1,
          const float* __restrict__ b2, const float* __restrict__ b3,
          const float* __restrict__ W4, const float* __restrict__ b4p,
          const uint16_t* __restrict__ wsw, float* __restrict__ out) {
  __shared__ uint16_t hbuf[16384];          // 32 KB: [2 planes][32 r][256 k]

  const int tid = threadIdx.x;
  const int wv = tid >> 6;                  // wave 0..7 -> n-cols wv*32..+32
  const int lane = tid & 63;
  const int q = lane >> 4;                  // k-group / D-row-group
  const int c = lane & 15;                  // A-row / B-col / D-col lane
  const int blk = blockIdx.x;
  const int woff = (wv * 32 + c) * 32 + q * 8;  // B u16 offset in a plane, nt=0
  // A-read u16 offset: row=mt*16+c; (row&15)==c -> off(mt,kc) =
  //   (mt*16+c)*256 + (((kc*4+q)^c)<<3)
  const int abase = c * 256;                // mt adds 4096; kc/q via XOR below

  floatx4 acc[2][2];

  // ---- layer-1 A: load g (fp32) and truncation-split to hi/lo short8 ----
  short8 g_hi[2], g_lo[2];
#pragma unroll
  for (int mt = 0; mt < 2; ++mt) {
    int row = blk * 32 + mt * 16 + c;       // exact: no tail
    const float* gp = ea + (size_t)row * 32 + q * 8;
    floatx4 v0 = *(const floatx4*)gp;
    floatx4 v1 = *(const floatx4*)(gp + 4);
    float g8[8] = {v0[0], v0[1], v0[2], v0[3], v1[0], v1[1], v1[2], v1[3]};
#pragma unroll
    for (int j = 0; j < 8; ++j) {
      fu32 a_; a_.f = g8[j];
      g_hi[mt][j] = (short)(a_.u >> 16);
      fu32 h_; h_.u = a_.u & 0xffff0000u;
      fu32 l_; l_.f = g8[j] - h_.f;
      g_lo[mt][j] = (short)(l_.u >> 16);
    }
  }

  // ---- Layer 1 (K=32: one k-step, chunk 0) ----
  ZEROACC();
  KSTEP_G(g_hi, g_lo, wsw);
  EPILOGUE_SPLIT(b1);
  __syncthreads();                          // h1 visible to all waves

  // ---- Layers 2 and 3: 8 k-steps each, no inner barriers ----
#pragma unroll 1
  for (int lay = 0; lay < 2; ++lay) {
    ZEROACC();
#pragma unroll
    for (int kc = 0; kc < 8; ++kc) {
      const uint16_t* wg = wsw + (size_t)(1 + lay * 8 + kc) * 16384;
      // A-frags: raw b128 reads from hi/lo planes (no unpack)
      short8 ahi[2], alo[2];
#pragma unroll
      for (int mt = 0; mt < 2; ++mt) {
        const int off = mt * 4096 + abase + (((kc * 4 + q) ^ c) << 3);
        ahi[mt] = *(const short8*)(hbuf + off);
        alo[mt] = *(const short8*)(hbuf + 8192 + off);
      }
      KSTEP_G(ahi, alo, wg);
    }
    if (lay == 0) {
      __syncthreads();                      // all waves done READING h1
      EPILOGUE_SPLIT(b2);                   // overwrite planes with h2
      __syncthreads();                      // h2 visible
    }
  }

  // ---- Layer 3 epilogue fused with Layer 4 (dot with W4) ----
  float p[2][4];
#pragma unroll
  for (int mt = 0; mt < 2; ++mt)
#pragma unroll
    for (int rr = 0; rr < 4; ++rr) p[mt][rr] = 0.0f;
#pragma unroll
  for (int nt = 0; nt < 2; ++nt) {
    const int k = wv * 32 + nt * 16 + c;
    float bv = b3[k];
    float wv4 = W4[k];
#pragma unroll
    for (int mt = 0; mt < 2; ++mt)
#pragma unroll
      for (int rr = 0; rr < 4; ++rr)
        p[mt][rr] += tanh_fast(acc[mt][nt][rr] + bv) * wv4;
  }
  // reduce across the 16 column-lanes (xor 1,2,4,8 stays in each 16-group)
#pragma unroll
  for (int off = 1; off < 16; off <<= 1)
#pragma unroll
    for (int mt = 0; mt < 2; ++mt)
#pragma unroll
      for (int rr = 0; rr < 4; ++rr)
        p[mt][rr] += __shfl_xor(p[mt][rr], off, 64);
  __syncthreads();                          // all waves done READING h2
  // cross-wave reduction: red[8 waves][32 rows] floats (1KB, reuse hbuf)
  float* red = (float*)hbuf;
  if (c == 0) {
#pragma unroll
    for (int mt = 0; mt < 2; ++mt)
#pragma unroll
      for (int rr = 0; rr < 4; ++rr)
        red[wv * 32 + mt * 16 + q * 4 + rr] = p[mt][rr];
  }
  __syncthreads();
  if (tid < 32) {
    float s = b4p[0];
#pragma unroll
    for (int w = 0; w < 8; ++w) s += red[w * 32 + tid];
    out[blk * 32 + tid] = log_sigmoid_f(s);
  }
}

extern "C" void kernel_launch(void* const* d_in, const int* in_sizes, int n_in,
                              void* d_out, int out_size, void* d_ws, size_t ws_size,
                              hipStream_t stream) {
  // setup_inputs order: x(0), edge_index(1), edge_attr(2), W1(3), b1(4),
  //                     W2(5), b2(6), W3(7), b3(8), W4(9), b4(10)
  const float* ea = (const float*)d_in[2];
  const float* W1 = (const float*)d_in[3];
  const float* b1 = (const float*)d_in[4];
  const float* W2 = (const float*)d_in[5];
  const float* b2 = (const float*)d_in[6];
  const float* W3 = (const float*)d_in[7];
  const float* b3 = (const float*)d_in[8];
  const float* W4 = (const float*)d_in[9];
  const float* b4 = (const float*)d_in[10];

  // needs NCH*32KB = 544KB of ws
  pack_weights<<<(NCH * 8192 + 255) / 256, 256, 0, stream>>>(
      W1, W2, W3, (uint16_t*)d_ws);
  mlp_fused<<<NBLK, 512, 0, stream>>>(ea, b1, b2, b3, W4, b4,
                                      (const uint16_t*)d_ws, (float*)d_out);
}